// Round 4
// baseline (234.933 us; speedup 1.0000x reference)
//
#include <hip/hip_runtime.h>
#include <math.h>

#define B_ 128
#define G_ 16
#define A_ 8732
#define C_ 21
#define THR_ 0.5f
#define NEG_POS_ 3
#define VAR0_ 0.1f
#define VAR1_ 0.2f

#define TPB_  768                 // 12 waves/block; VGPR cap 170 -> no spill of xx[84]
#define NW_   (TPB_ / 64)         // 12
#define NGRP_ (A_ / 4)            // 2183 groups of 4 anchors (8732 = 4*2183 exactly)
#define NPTS_ 12                  // ceil(A_/TPB_) for select scan

// ---------------------------------------------------------------------------
// Fused per-batch kernel: match -> loss -> hard-negative select.
// One block per batch; all per-batch state lives in LDS (~46 KB).
// No global intermediates, no atomics.
// ---------------------------------------------------------------------------
__global__ __launch_bounds__(TPB_) void k_fused(
    const float* __restrict__ pred_off,   // B,A,4
    const float* __restrict__ pred_conf,  // B,A,C
    const float* __restrict__ tboxes,     // B,G,4 (point form)
    const int*   __restrict__ tlabels,    // B,G
    const float* __restrict__ anchors,    // A,4 (center form)
    float*       __restrict__ part_loc,   // B
    float*       __restrict__ part_cls,   // B
    int*         __restrict__ num_pos)    // B
{
    const int b    = blockIdx.x;
    const int tid  = threadIdx.x;
    const int lane = tid & 63;
    const int w    = tid >> 6;            // 0..11

    __shared__ float         s_ov[A_];    // phase M: best iou; phase L+: aux (bit-reused)
    __shared__ unsigned char s_gi[A_];
    __shared__ float s_boxlds[G_ * 4];
    __shared__ int   s_lab[G_];
    __shared__ unsigned long long s_gb[NW_ * G_];
    __shared__ int   s_forced[G_];
    __shared__ int   s_i1[NW_];
    __shared__ float s_f1[NW_], s_f2[NW_], s_f3[NW_];
    __shared__ int   s_c[2][NW_];
    __shared__ int   s_K;

    // ---------------- phase M: matching ----------------
    if (tid < G_ * 4) s_boxlds[tid] = tboxes[b * G_ * 4 + tid];
    if (tid < G_)     s_lab[tid]    = tlabels[b * G_ + tid];
    __syncthreads();

    float bx0[G_], by0[G_], bx1[G_], by1[G_], bar[G_];
    #pragma unroll
    for (int g = 0; g < G_; ++g) {
        bx0[g] = s_boxlds[g * 4 + 0];
        by0[g] = s_boxlds[g * 4 + 1];
        bx1[g] = s_boxlds[g * 4 + 2];
        by1[g] = s_boxlds[g * 4 + 3];
        bar[g] = (bx1[g] - bx0[g]) * (by1[g] - by0[g]);
    }

    unsigned long long gb[G_];
    #pragma unroll
    for (int g = 0; g < G_; ++g) gb[g] = 0ull;

    for (int a = tid; a < A_; a += TPB_) {
        float4 an = ((const float4*)anchors)[a];
        float ax0 = an.x - an.z * 0.5f, ay0 = an.y - an.w * 0.5f;
        float ax1 = an.x + an.z * 0.5f, ay1 = an.y + an.w * 0.5f;
        float area_b = (ax1 - ax0) * (ay1 - ay0);   // mirror reference arithmetic
        float bov = -1.f; int bg = 0;
        #pragma unroll
        for (int g = 0; g < G_; ++g) {
            float tlx = fmaxf(bx0[g], ax0);
            float tly = fmaxf(by0[g], ay0);
            float brx = fminf(bx1[g], ax1);
            float bry = fminf(by1[g], ay1);
            float wdt = fmaxf(brx - tlx, 0.f);
            float hgt = fmaxf(bry - tly, 0.f);
            float inter = wdt * hgt;
            float iou = inter / (bar[g] + area_b - inter);   // IEEE div (bit-exact vs ref)
            if (iou > bov) { bov = iou; bg = g; }            // first g wins on ties
            unsigned long long pk =
                ((unsigned long long)__float_as_uint(iou) << 32) |
                (unsigned)(~(unsigned)a);                    // max iou, min a on ties
            if (pk > gb[g]) gb[g] = pk;
        }
        s_ov[a] = bov;
        s_gi[a] = (unsigned char)bg;
    }

    #pragma unroll
    for (int g = 0; g < G_; ++g) {
        #pragma unroll
        for (int off = 32; off > 0; off >>= 1) {
            unsigned long long o = __shfl_down(gb[g], off);
            if (o > gb[g]) gb[g] = o;
        }
    }
    if (lane == 0) {
        #pragma unroll
        for (int g = 0; g < G_; ++g) s_gb[w * G_ + g] = gb[g];
    }
    __syncthreads();
    if (tid < G_) {
        unsigned long long m = 0ull;
        #pragma unroll
        for (int wv = 0; wv < NW_; ++wv) {
            unsigned long long v = s_gb[wv * G_ + tid];
            if (v > m) m = v;
        }
        s_forced[tid] = (int)(~(unsigned)(m & 0xFFFFFFFFull));
    }
    __syncthreads();
    if (tid == 0) {
        for (int g = 0; g < G_; ++g) {      // ascending g, last write wins (ref loop)
            int a = s_forced[g];
            s_ov[a] = 1.0f;
            s_gi[a] = (unsigned char)g;
        }
    }
    __syncthreads();

    // ---------------- phase L: per-anchor loss ----------------
    // Thread t owns groups {t, t+768, t+1536} (< 2183); each group = 4 anchors
    // = 21 aligned float4 loads, register-resident. conf derived inline from
    // s_ov/s_gi; aux written in place over s_ov (same-thread read-then-write).
    float lloc = 0.f, pnll = 0.f;
    int   cnt  = 0;

    for (int j = 0; j < 3; ++j) {
        int gid = tid + j * TPB_;
        if (gid < NGRP_) {
            const float4* cp = (const float4*)pred_conf + ((size_t)b * NGRP_ + gid) * 21;
            float xx[84];
            #pragma unroll
            for (int k = 0; k < 21; ++k) {
                float4 v = cp[k];
                xx[4 * k + 0] = v.x; xx[4 * k + 1] = v.y;
                xx[4 * k + 2] = v.z; xx[4 * k + 3] = v.w;
            }
            #pragma unroll
            for (int jj = 0; jj < 4; ++jj) {
                const int base = 21 * jj;
                const int a    = 4 * gid + jj;
                float ov = s_ov[a];
                int   g  = s_gi[a];
                int conf = (ov < THR_) ? 0 : (s_lab[g] + 1);

                float m = xx[base];
                #pragma unroll
                for (int c = 1; c < C_; ++c) m = fmaxf(m, xx[base + c]);
                float s = 0.f;
                #pragma unroll
                for (int c = 0; c < C_; ++c) s += __expf(xx[base + c] - m);
                float lse = m + __logf(s);

                float xc = xx[base];
                #pragma unroll
                for (int c = 1; c < C_; ++c) xc = (conf == c) ? xx[base + c] : xc;
                float nll = lse - xc;
                bool pos = conf > 0;
                s_ov[a] = pos ? 0.f : nll;          // aux, in place

                if (pos) {
                    cnt++;
                    pnll += nll;
                    float4 an = ((const float4*)anchors)[a];
                    float4 bx = ((const float4*)tboxes)[b * G_ + g];
                    float gcx = (bx.x + bx.z) * 0.5f, gcy = (bx.y + bx.w) * 0.5f;
                    float gw = bx.z - bx.x, gh = bx.w - bx.y;
                    float l0 = (gcx - an.x) / (an.z * VAR0_);
                    float l1 = (gcy - an.y) / (an.w * VAR0_);
                    float l2 = logf(gw / an.z) / VAR1_;
                    float l3 = logf(gh / an.w) / VAR1_;
                    float4 p = ((const float4*)pred_off)[(size_t)b * A_ + a];
                    float d, ad;
                    d = p.x - l0; ad = fabsf(d); lloc += (ad < 1.f) ? 0.5f * d * d : ad - 0.5f;
                    d = p.y - l1; ad = fabsf(d); lloc += (ad < 1.f) ? 0.5f * d * d : ad - 0.5f;
                    d = p.z - l2; ad = fabsf(d); lloc += (ad < 1.f) ? 0.5f * d * d : ad - 0.5f;
                    d = p.w - l3; ad = fabsf(d); lloc += (ad < 1.f) ? 0.5f * d * d : ad - 0.5f;
                }
            }
        }
    }

    // num_pos reduction (needed for K before select)
    int cw = cnt;
    #pragma unroll
    for (int off = 32; off > 0; off >>= 1) cw += __shfl_down(cw, off);
    if (lane == 0) s_i1[w] = cw;
    __syncthreads();                       // also covers all s_ov aux writes
    if (tid == 0) {
        int np = 0;
        #pragma unroll
        for (int wv = 0; wv < NW_; ++wv) np += s_i1[wv];
        num_pos[b] = np;
        s_K = min(NEG_POS_ * np, A_ - 1);
    }
    __syncthreads();
    const int K = s_K;

    // ---------------- phase S: exact K-th largest over LDS aux ----------------
    unsigned lo = 0u, hi = 0x7f800000u;
    int it = 0;
    while (lo < hi) {
        unsigned mid = (lo + hi) >> 1;
        int c = 0;
        #pragma unroll
        for (int j = 0; j < NPTS_; ++j) {
            int a = tid + j * TPB_;
            if (a < A_) c += (__float_as_uint(s_ov[a]) > mid);
        }
        #pragma unroll
        for (int off = 32; off > 0; off >>= 1) c += __shfl_down(c, off);
        if (lane == 0) s_c[it & 1][w] = c;
        __syncthreads();
        int total = 0;
        #pragma unroll
        for (int wv = 0; wv < NW_; ++wv) total += s_c[it & 1][wv];
        if (total >= K) lo = mid + 1; else hi = mid;
        ++it;
    }
    // lo == bit pattern of T = K-th largest aux

    int c2 = 0; float sm = 0.f;
    #pragma unroll
    for (int j = 0; j < NPTS_; ++j) {
        int a = tid + j * TPB_;
        if (a < A_) {
            unsigned u = __float_as_uint(s_ov[a]);
            if (u > lo) { c2++; sm += __uint_as_float(u); }
        }
    }

    // ---------------- final block reductions ----------------
    #pragma unroll
    for (int off = 32; off > 0; off >>= 1) {
        lloc += __shfl_down(lloc, off);
        pnll += __shfl_down(pnll, off);
        sm   += __shfl_down(sm, off);
        c2   += __shfl_down(c2, off);
    }
    if (lane == 0) { s_f1[w] = lloc; s_f2[w] = pnll; s_f3[w] = sm; s_i1[w] = c2; }
    __syncthreads();
    if (tid == 0) {
        float L = 0.f, P = 0.f, S = 0.f; int Ct = 0;
        #pragma unroll
        for (int wv = 0; wv < NW_; ++wv) {
            L += s_f1[wv]; P += s_f2[wv]; S += s_f3[wv]; Ct += s_i1[wv];
        }
        float T = __uint_as_float(lo);
        part_loc[b] = L;
        part_cls[b] = P + S + (float)(K - Ct) * T;
    }
}

// ---------------------------------------------------------------------------
// Final: reduce 128 per-batch partials, divide by n_total.
// ---------------------------------------------------------------------------
__global__ __launch_bounds__(128) void k_final(
    const float* __restrict__ part_loc,
    const float* __restrict__ part_cls,
    const int*   __restrict__ num_pos,
    float*       __restrict__ out)
{
    const int tid  = threadIdx.x;
    const int lane = tid & 63;
    const int w    = tid >> 6;
    __shared__ float s_l[2], s_c[2];
    __shared__ int   s_n[2];

    float L = part_loc[tid], Cc = part_cls[tid];
    int   N = num_pos[tid];
    #pragma unroll
    for (int off = 32; off > 0; off >>= 1) {
        L  += __shfl_down(L, off);
        Cc += __shfl_down(Cc, off);
        N  += __shfl_down(N, off);
    }
    if (lane == 0) { s_l[w] = L; s_c[w] = Cc; s_n[w] = N; }
    __syncthreads();
    if (tid == 0) {
        float n = (float)(s_n[0] + s_n[1]);
        out[0] = (s_l[0] + s_l[1]) / n;
        out[1] = (s_c[0] + s_c[1]) / n;
    }
}

// ---------------------------------------------------------------------------
extern "C" void kernel_launch(void* const* d_in, const int* in_sizes, int n_in,
                              void* d_out, int out_size, void* d_ws, size_t ws_size,
                              hipStream_t stream) {
    const float* pred_off  = (const float*)d_in[0];  // B,A,4
    const float* pred_conf = (const float*)d_in[1];  // B,A,C
    const float* tboxes    = (const float*)d_in[2];  // B,G,4
    const int*   tlabels   = (const int*)  d_in[3];  // B,G
    const float* anchors   = (const float*)d_in[4];  // A,4
    float* out = (float*)d_out;

    char* ws = (char*)d_ws;
    float* ploc_ws = (float*)ws;   ws += (size_t)B_ * sizeof(float);
    float* pcls_ws = (float*)ws;   ws += (size_t)B_ * sizeof(float);
    int*   npos_ws = (int*)ws;     ws += (size_t)B_ * sizeof(int);

    k_fused<<<B_, TPB_, 0, stream>>>(pred_off, pred_conf, tboxes, tlabels, anchors,
                                     ploc_ws, pcls_ws, npos_ws);
    k_final<<<1, 128, 0, stream>>>(ploc_ws, pcls_ws, npos_ws, out);
}